// Round 4
// baseline (265.392 us; speedup 1.0000x reference)
//
#include <hip/hip_runtime.h>
#include <math.h>

// Problem constants (B,S,D,H) = (4,2048,1024,16), HD=64
#define BATCH 4
#define SEQ   2048
#define DMODEL 1024
#define NHEAD 16
#define HDIM  64
#define MROWS (BATCH*SEQ)   // 8192

typedef unsigned short u16;
typedef unsigned int   u32;

using bf16x8 = __attribute__((ext_vector_type(8))) short;
using f32x4  = __attribute__((ext_vector_type(4))) float;
using f32x16 = __attribute__((ext_vector_type(16))) float;
using u32x4  = __attribute__((ext_vector_type(4))) unsigned int;

__device__ __forceinline__ u16 f2bf(float f) {
    u32 u = __float_as_uint(f);
    u += 0x7fffu + ((u >> 16) & 1u);
    return (u16)(u >> 16);
}
__device__ __forceinline__ u32 pack2bf(float a, float b) {
    u32 ua = __float_as_uint(a); ua += 0x7fffu + ((ua >> 16) & 1u);
    u32 ub = __float_as_uint(b); ub += 0x7fffu + ((ub >> 16) & 1u);
    return (ua >> 16) | (ub & 0xffff0000u);
}
// packed f32->bf16x2 via HW instruction (src0 -> low half)
__device__ __forceinline__ u32 cvtpk(float a, float b) {
    u32 r;
    asm("v_cvt_pk_bf16_f32 %0, %1, %2" : "=v"(r) : "v"(a), "v"(b));
    return r;
}
// swap upper 32 lanes of a with lower 32 lanes of b
#define PLSWAP(a, b) asm("v_permlane32_swap_b32 %0, %1" : "+v"(a), "+v"(b))

// async global->LDS, 16 B per lane; LDS dest = wave-uniform base + lane*16
#define GLOBAL_LOAD_LDS16(gp, lp)                                              \
    __builtin_amdgcn_global_load_lds(                                          \
        (const __attribute__((address_space(1))) void*)(gp),                   \
        (__attribute__((address_space(3))) void*)(lp), 16, 0, 0)

// ---------------------------------------------------------------------------
// Convert x (8.4M) + Wq/Wk/Wv/Wo (1M each) fp32 -> bf16 into contiguous dst.
// ---------------------------------------------------------------------------
__global__ __launch_bounds__(256) void convert_inputs(
    const float* __restrict__ x,  const float* __restrict__ wq,
    const float* __restrict__ wk, const float* __restrict__ wv,
    const float* __restrict__ wo, u16* __restrict__ dst)
{
    long long i4 = ((long long)blockIdx.x * 256 + threadIdx.x) * 4;
    const float* src; long long off;
    if (i4 < 8388608LL) { src = x; off = i4; }
    else {
        long long j = i4 - 8388608LL;
        int seg = (int)(j >> 20);
        off = j & 1048575LL;
        src = (seg == 0) ? wq : (seg == 1) ? wk : (seg == 2) ? wv : wo;
    }
    float4 v = *(const float4*)(src + off);
    u32 lo = (u32)f2bf(v.x) | ((u32)f2bf(v.y) << 16);
    u32 hi = (u32)f2bf(v.z) | ((u32)f2bf(v.w) << 16);
    *(uint2*)(dst + i4) = make_uint2(lo, hi);
}

// ---------------------------------------------------------------------------
// bf16 MFMA GEMM — m201-style 256x256 8-phase schedule (T2+T3+T4+T5).
//   512 threads = 8 waves (2M x 4N); per-wave output 128x64; acc[8][4].
//   BK=64; LDS = 2dbuf x (A 256x64 + B 256x64) bf16 = 128 KiB.
//   Per phase: {ds_read subtile (4 A-frags; +8 B-frags at q0) ; stage one
//   64-row half (2 global_load_lds) ; barrier ; lgkmcnt(0)+sched_barrier ;
//   setprio(1) 16 MFMA setprio(0) ; [vmcnt(6) at p3/p7] ; barrier}.
//   Stage stream per tile: B0 B1 | B2 B3 | A0 A2 | A1 A3 with 4-phase lead;
//   region liveness: B dead after q0-phase, A0/A2 after q1, A1/A3 after q3.
//   vmcnt(6) at phase3/7-end => previous tile fully landed; never 0 in loop.
//   Rows = 64 shorts (128 B, 8 chunks); XOR swizzle chunk_phys =
//   chunk_log ^ (row&7) via pre-swizzled global source + swizzled ds_read.
//   QKV=1: N=3072 fused (Wq/Wk/Wv contiguous); seg epilogues:
//     0: RoPE * (0.125*log2e)  1: RoPE  2: V^T store via LDS transpose.
//   QKV=0: fp32 output + bias (final projection).
// ---------------------------------------------------------------------------
template<int QKV>
__global__ __launch_bounds__(512) void gemm_mfma(
    const u16* __restrict__ A,
    const u16* __restrict__ Wq_, const u16* __restrict__ Wk_, const u16* __restrict__ Wv_,
    const float* __restrict__ bq_, const float* __restrict__ bk_, const float* __restrict__ bv_,
    u16* __restrict__ Cq_, u16* __restrict__ Ck_, u16* __restrict__ Cv_,
    float* __restrict__ Cf)
{
    // A: [2 dbuf][256][64] @ 0 ; B: [2 dbuf][256][64] @ 32768 (shorts)
    __shared__ __align__(16) u16 smem[65536];   // 128 KiB

    const int t    = threadIdx.x;
    const int lane = t & 63;
    const int w    = t >> 6;        // 0..7
    const int quad = lane >> 4;
    const int l15  = lane & 15;
    const int wm   = w >> 2;        // 0..1 (M)
    const int wn   = w & 3;         // 0..3 (N)

    const int bx  = blockIdx.x;
    const int xcd = bx & 7;
    const int i_  = bx >> 3;
    const int bml = i_ & 3;
    const int n_  = i_ >> 2;                    // QKV: 0..11, proj: 0..3
    const int seg = (QKV ? (n_ >> 2) : 0);
    const int nn  = (QKV ? (n_ & 3) : n_);

    const u16*   W    = (seg == 0) ? Wq_ : (seg == 1) ? Wk_ : Wv_;
    const float* bias = (seg == 0) ? bq_ : (seg == 1) ? bk_ : bv_;
    u16*         Cb   = (seg == 0) ? Cq_ : (seg == 1) ? Ck_ : Cv_;

    const int bm = (xcd * 4 + bml) * 256;
    const int bn = nn * 256;

    // staging map: lane -> row 8w+(lane>>3), phys chunk lane&7,
    // source chunk = (lane&7)^(row&7)
    const int sr8 = lane >> 3;
    const int scl = (lane & 7) ^ sr8;
    const u16* gA = A + (size_t)(bm + 8 * w + sr8) * DMODEL + scl * 8;
    const u16* gB = W + (size_t)(bn + 8 * w + sr8) * DMODEL + scl * 8;

#define STG_A(rg, kt, bs)                                                      \
    GLOBAL_LOAD_LDS16(gA + (size_t)(rg) * 64 * DMODEL + (kt) * 64,             \
                      &smem[(bs) * 16384 + ((rg) * 64 + 8 * w) * 64])
#define STG_B(rg, kt, bs)                                                      \
    GLOBAL_LOAD_LDS16(gB + (size_t)(rg) * 64 * DMODEL + (kt) * 64,             \
                      &smem[32768 + (bs) * 16384 + ((rg) * 64 + 8 * w) * 64])

    // ---- prologue: tile0 (buf0) all 8 halves; tile1 (buf1) first 6 halves
    STG_B(0, 0, 0); STG_B(1, 0, 0); STG_B(2, 0, 0); STG_B(3, 0, 0);
    STG_A(0, 0, 0); STG_A(2, 0, 0); STG_A(1, 0, 0); STG_A(3, 0, 0);
    STG_B(0, 1, 1); STG_B(1, 1, 1); STG_B(2, 1, 1); STG_B(3, 1, 1);
    STG_A(0, 1, 1); STG_A(2, 1, 1);
    asm volatile("s_waitcnt vmcnt(6)" ::: "memory");   // tile 0 landed
    __builtin_amdgcn_s_barrier();

    const int cA0 = (quad ^ (l15 & 7)) * 8;   // K-half0 chunk offset; half1 = ^32

    f32x4 acc[8][4] = {};
    bf16x8 bfr[4][2];

#define LOAD_B(Bb) {                                                           \
    _Pragma("unroll")                                                          \
    for (int j = 0; j < 4; ++j) {                                              \
        bfr[j][0] = *(const bf16x8*)&(Bb)[(wn * 64 + 16 * j + l15) * 64 + cA0];\
        bfr[j][1] = *(const bf16x8*)&(Bb)[(wn * 64 + 16 * j + l15) * 64 + (cA0 ^ 32)];\
    } }
#define PHASE(q, Ab, Bb, STAGES, CKPT) {                                       \
    bf16x8 af_[2][2];                                                          \
    if ((q) == 0) LOAD_B(Bb);                                                  \
    _Pragma("unroll")                                                          \
    for (int ii = 0; ii < 2; ++ii) {                                           \
        const int r_ = (wm * 128 + (q) * 32 + 16 * ii + l15) * 64;             \
        af_[ii][0] = *(const bf16x8*)&(Ab)[r_ + cA0];                          \
        af_[ii][1] = *(const bf16x8*)&(Ab)[r_ + (cA0 ^ 32)];                   \
    }                                                                          \
    STAGES;                                                                    \
    __builtin_amdgcn_s_barrier();                                              \
    asm volatile("s_waitcnt lgkmcnt(0)" ::: "memory");                         \
    __builtin_amdgcn_sched_barrier(0);                                         \
    __builtin_amdgcn_s_setprio(1);                                             \
    _Pragma("unroll")                                                          \
    for (int ii = 0; ii < 2; ++ii)                                             \
        _Pragma("unroll")                                                      \
        for (int j = 0; j < 4; ++j) {                                          \
            acc[2*(q)+ii][j] = __builtin_amdgcn_mfma_f32_16x16x32_bf16(        \
                af_[ii][0], bfr[j][0], acc[2*(q)+ii][j], 0, 0, 0);             \
            acc[2*(q)+ii][j] = __builtin_amdgcn_mfma_f32_16x16x32_bf16(        \
                af_[ii][1], bfr[j][1], acc[2*(q)+ii][j], 0, 0, 0);             \
        }                                                                      \
    __builtin_amdgcn_s_setprio(0);                                             \
    CKPT;                                                                      \
    __builtin_amdgcn_s_barrier();                                              \
}

    #pragma unroll 1
    for (int i = 0; i < 8; ++i) {
        const bool st = (i < 7);
        const int  kn = 2 * i + 2, kn3 = 2 * i + 3, ko = 2 * i + 1;
        // ---- K-tile 2i from buf0
        {
            const u16* Ab = smem;
            const u16* Bb = smem + 32768;
            PHASE(0, Ab, Bb, { STG_A(1, ko, 1); STG_A(3, ko, 1); }, {});
            PHASE(1, Ab, Bb, { if (st) { STG_B(0, kn, 0); STG_B(1, kn, 0); } }, {});
            PHASE(2, Ab, Bb, { if (st) { STG_B(2, kn, 0); STG_B(3, kn, 0); } }, {});
            PHASE(3, Ab, Bb, { if (st) { STG_A(0, kn, 0); STG_A(2, kn, 0); } },
                  { if (st) asm volatile("s_waitcnt vmcnt(6)" ::: "memory");
                    else    asm volatile("s_waitcnt vmcnt(0)" ::: "memory"); });
        }
        // ---- K-tile 2i+1 from buf1
        {
            const u16* Ab = smem + 16384;
            const u16* Bb = smem + 32768 + 16384;
            PHASE(0, Ab, Bb, { if (st) { STG_A(1, kn, 0); STG_A(3, kn, 0); } }, {});
            PHASE(1, Ab, Bb, { if (st) { STG_B(0, kn3, 1); STG_B(1, kn3, 1); } }, {});
            PHASE(2, Ab, Bb, { if (st) { STG_B(2, kn3, 1); STG_B(3, kn3, 1); } }, {});
            PHASE(3, Ab, Bb, { if (st) { STG_A(0, kn3, 1); STG_A(2, kn3, 1); } },
                  { if (st) asm volatile("s_waitcnt vmcnt(6)" ::: "memory");
                    else    asm volatile("s_waitcnt vmcnt(0)" ::: "memory"); });
        }
    }
#undef PHASE
#undef LOAD_B
#undef STG_A
#undef STG_B

    // ---- epilogue (wave rows: wm*128 + 16*ri + quad*4 + r; cols: wn*64 + 16j + l15)
    const int wrow = wm * 128;
    const int wcol = wn * 64;
    float bvv[4];
    #pragma unroll
    for (int j = 0; j < 4; j++) bvv[j] = bias[bn + wcol + 16 * j + l15];

    if constexpr (QKV == 0) {
        #pragma unroll
        for (int ri = 0; ri < 8; ri++)
            #pragma unroll
            for (int r = 0; r < 4; r++) {
                int mg = bm + wrow + 16 * ri + quad * 4 + r;
                #pragma unroll
                for (int j = 0; j < 4; j++)
                    Cf[(size_t)mg * DMODEL + bn + wcol + 16 * j + l15] = acc[ri][j][r] + bvv[j];
            }
    } else {
        if (seg == 2) {
            // ---- V^T store: transpose 256(s) x 256(d) tile via LDS.
            // T logical [row=d 0..255][col=s 0..255] bf16 (512-B rows),
            // byte-swizzled: byte ^= (row&7)<<4 (16-B granular, 8-way).
            u16* T = smem;   // 128 KiB, buffers dead
            #pragma unroll
            for (int ri = 0; ri < 8; ri++) {
                #pragma unroll
                for (int j = 0; j < 4; j++) {
                    int col = wrow + 16 * ri + quad * 4;  // s-local (r adds 0..3)
                    int row = wcol + 16 * j + l15;        // d-local 0..255
                    u32 lo = pack2bf(acc[ri][j][0] + bvv[j], acc[ri][j][1] + bvv[j]);
                    u32 hi = pack2bf(acc[ri][j][2] + bvv[j], acc[ri][j][3] + bvv[j]);
                    *(uint2*)((char*)T + row * 512 + ((col * 2) ^ ((row & 7) << 4)))
                        = make_uint2(lo, hi);
                }
            }
            __syncthreads();
            {
                int row = t >> 1, half = t & 1;           // 256 rows x 2 halves
                int hgl = (bn + row) >> 6;
                int dl  = (bn + row) & 63;
                int bb  = bm >> 11;
                size_t obase = (((size_t)(bb * NHEAD + hgl)) * HDIM + dl) * SEQ
                             + (bm & (SEQ - 1)) + half * 128;
                #pragma unroll
                for (int k = 0; k < 16; k++) {
                    uint4 vv = *(const uint4*)((const char*)T + row * 512
                                 + ((half * 256 + k * 16) ^ ((row & 7) << 4)));
                    *(uint4*)(Cb + obase + k * 8) = vv;
                }
            }
        } else {
            // RoPE: wave's 64-col span = one head; pair (d, d+32) = j-tiles (j, j+2)
            // Q additionally scaled by 0.125 * log2(e) so attn uses exp2 directly.
            const float qscale = (seg == 0) ? 0.18033688011112042f : 1.0f;
            float inv[2];
            #pragma unroll
            for (int j = 0; j < 2; j++) {
                int d = 16 * j + l15;                              // 0..31
                inv[j] = exp2f(-(float)d * 0.4152410118609203f);   // 10000^(-d/32)
            }
            #pragma unroll
            for (int ri = 0; ri < 8; ri++)
                #pragma unroll
                for (int r = 0; r < 4; r++) {
                    int mg = bm + wrow + 16 * ri + quad * 4 + r;
                    int s  = mg & (SEQ - 1);
                    #pragma unroll
                    for (int j = 0; j < 2; j++) {
                        float f = (float)s * inv[j];
                        float sn, cs;
                        __sincosf(f, &sn, &cs);
                        float a1 = acc[ri][j][r]     + bvv[j];
                        float a2 = acc[ri][j + 2][r] + bvv[j + 2];
                        float o1 = (a1 * cs - a2 * sn) * qscale;
                        float o2 = (a2 * cs + a1 * sn) * qscale;
                        Cb[(size_t)mg * DMODEL + bn + wcol + 16 * j       + l15] = f2bf(o1);
                        Cb[(size_t)mg * DMODEL + bn + wcol + 16 * (j + 2) + l15] = f2bf(o2);
                    }
                }
        }
    }
}

// ---------------------------------------------------------------------------
// MFMA flash attention v3: 32x32x16, 128 q-rows/block, max-free softmax.
// S^T = K*Q^T so P is lane-local; P->bf16 A-frags built IN REGISTER via
// v_cvt_pk_bf16_f32 + v_permlane32_swap_b32 (no P LDS bounce).  V arrives
// pre-transposed (V^T[b][h][d][s]) and is staged like K via global_load_lds.
// K/V double-buffered, single barrier + vmcnt(0) per tile; buffer 1 aliases
// the dead Q staging area -> 33,280 B LDS, 4 blocks/CU (all 1024 resident).
// ---------------------------------------------------------------------------
__global__ __launch_bounds__(256) void attn_mfma(
    const u16* __restrict__ Q, const u16* __restrict__ K,
    const u16* __restrict__ VT, u16* __restrict__ O)
{
    __shared__ __align__(16) u16 smem[16640];   // 33,280 B
    u16* const Qs  = smem;                      // bytes [0,16384)
    u16* const Ks0 = smem + 8192;               // [16384,24576)
    u16* const Ks1 = smem;                      // alias Qs lo half [0,8192)
    u16* const Vt0 = smem + 12288;              // [24576,32768)
    u16* const Vt1 = smem + 4096;               // alias Qs hi half [8192,16384)
    float* const lS = (float*)(smem + 16384);   // [32768,33280)

    const int t    = threadIdx.x;
    const int lane = t & 63;
    const int w    = t >> 6;
    const int l31  = lane & 31;
    const int hl   = lane >> 5;         // 0/1
    const int bid  = blockIdx.x;
    const int bh   = bid & 63;
    // per-CU balanced qt map: CU hosts x, x+4, x+8, x+12 -> equal tile sums
    const int x_   = bid >> 6, g_ = x_ >> 2, r_ = x_ & 3;
    const int qt   = (g_ == 0) ? 15 - r_ : (g_ == 1) ? 8 + r_
                   : (g_ == 2) ? 4 + r_ : 3 - r_;
    const int h    = bh & (NHEAD - 1);
    const int b    = bh >> 4;
    const int q0   = qt * 128;

    const size_t gbase = ((size_t)b * SEQ) * DMODEL + h * HDIM;
    const size_t vbase = ((size_t)(b * NHEAD + h)) * HDIM * SEQ;

    const int rl  = lane >> 3;
    const int csw = (lane & 7) ^ rl;    // pre-swizzled source chunk

    // ---- prologue: stage Q (4 issues) + K/V^T tile 0 (2+2 issues)
    #pragma unroll
    for (int i = 0; i < 4; i++) {
        int row = 32 * w + 8 * i + rl;
        GLOBAL_LOAD_LDS16(Q + gbase + (size_t)(q0 + row) * DMODEL + csw * 8,
                          &Qs[(32 * w + 8 * i) * 64]);
    }
    #pragma unroll
    for (int i = 0; i < 2; i++) {
        int row = 16 * w + 8 * i + rl;
        GLOBAL_LOAD_LDS16(K + gbase + (size_t)row * DMODEL + csw * 8,
                          &Ks0[(16 * w + 8 * i) * 64]);
        GLOBAL_LOAD_LDS16(VT + vbase + (size_t)row * SEQ + csw * 8,
                          &Vt0[(16 * w + 8 * i) * 64]);
    }
    __syncthreads();

    // ---- hoist Q B-fragments: B[k][n=q], k = hl*8+e (+16*stp)
    bf16x8 qf[4];
    {
        int row = 32 * w + l31;
        #pragma unroll
        for (int s = 0; s < 4; s++) {
            int c = (hl + 2 * s) ^ (row & 7);
            qf[s] = *(const bf16x8*)&Qs[row * 64 + c * 8];
        }
    }
    __syncthreads();   // Qs dead; aliased buffer 1 may now be staged

    float lsum = 0.0f;
    f32x16 oacc[2] = {};
    const int qg   = q0 + 32 * w + l31;
    const int qmax = q0 + 32 * w + 31;

// S^T quadrant KRH: 4 MFMA, mask, exp2, tree-sum, in-register P->bf16 frags.
#define QUADRANT(KRH, F0, F1) do {                                             \
    f32x16 s_ = {};                                                            \
    __builtin_amdgcn_s_setprio(1);                                             \
    _Pragma("unroll")                                                          \
    for (int stp_ = 0; stp_ < 4; ++stp_) {                                     \
        int c_ = ((hl + 2 * stp_) ^ (l31 & 7)) * 8;                            \
        bf16x8 ka_ = *(const bf16x8*)&Ksb[(32 * (KRH) + l31) * 64 + c_];       \
        s_ = __builtin_amdgcn_mfma_f32_32x32x16_bf16(ka_, qf[stp_], s_, 0, 0, 0);\
    }                                                                          \
    __builtin_amdgcn_s_setprio(0);                                             \
    if (k0 + 32 * (KRH) + 31 > q0 + 32 * w) {                                  \
        _Pragma("unroll")                                                      \
        for (int rr_ = 0; rr_ < 16; ++rr_) {                                   \
            int krg_ = k0 + 32 * (KRH) + (rr_ & 3) + 8 * (rr_ >> 2) + 4 * hl;  \
            if (krg_ > qg) s_[rr_] = -1e30f;                                   \
        }                                                                      \
    }                                                                          \
    float pv_[16];                                                             \
    _Pragma("unroll")                                                          \
    for (int rr_ = 0; rr_ < 16; ++rr_) pv_[rr_] = __builtin_amdgcn_exp2f(s_[rr_]);\
    lsum += ((pv_[0]+pv_[1])+(pv_[2]+pv_[3])) + ((pv_[4]+pv_[5])+(pv_[6]+pv_[7]))\
          + ((pv_[8]+pv_[9])+(pv_[10]+pv_[11])) + ((pv_[12]+pv_[13])+(pv_[14]+pv_[15]));\
    u32 k01_ = cvtpk(pv_[0], pv_[1]),   k23_ = cvtpk(pv_[2], pv_[3]);          \
    u32 k45_ = cvtpk(pv_[4], pv_[5]),   k67_ = cvtpk(pv_[6], pv_[7]);          \
    u32 k89_ = cvtpk(pv_[8], pv_[9]),   kab_ = cvtpk(pv_[10], pv_[11]);        \
    u32 kcd_ = cvtpk(pv_[12], pv_[13]), kef_ = cvtpk(pv_[14], pv_[15]);        \
    PLSWAP(k01_, k45_); PLSWAP(k23_, k67_);                                    \
    PLSWAP(k89_, kcd_); PLSWAP(kab_, kef_);                                    \
    { union { u32x4 u; bf16x8 v; } c0_; c0_.u = (u32x4){k01_, k23_, k45_, k67_};\
      F0 = c0_.v; }                                                            \
    { union { u32x4 u; bf16x8 v; } c1_; c1_.u = (u32x4){k89_, kab_, kcd_, kef_};\
      F1 = c1_.v; }                                                            \
} while (0)

#define PVSTEP(STP, PF) do {                                                   \
    int c_ = ((hl + 2 * (STP)) ^ (l31 & 7)) * 8;                               \
    bf16x8 v0_ = *(const bf16x8*)&Vtb[l31 * 64 + c_];                          \
    bf16x8 v1_ = *(const bf16x8*)&Vtb[(32 + l31) * 64 + c_];                   \
    oacc[0] = __builtin_amdgcn_mfma_f32_32x32x16_bf16(PF, v0_, oacc[0], 0, 0, 0);\
    oacc[1] = __builtin_amdgcn_mfma_f32_32x32x16_bf16(PF, v1_, oacc[1], 0, 0, 0);\
} while (0)

    const int ktn = 2 * qt + 2;
    for (int kt = 0; kt < ktn; kt++) {
        const int k0 = kt * 64;
        u16* const Ksb = (kt & 1) ? Ks1 : Ks0;
        u16* const Vtb = (kt & 1) ? Vt1 : Vt0;

        // prefetch next tile into the other buffer (issue-early)
        if (kt + 1 < ktn) {
            u16* const Ksn = (kt & 1) ? Ks0 : Ks1;
            u16* const Vtn = (kt & 1) ? Vt0 : Vt1;
            const size_t kk0 = (size_t)(kt + 1) * 64;
            #pragma unroll
            for (int i = 0; i < 2; i++) {
                int row = 16 * w + 8 * i + rl;
                GLOBAL_LOAD_LDS16(K + gbase + (kk0 + row) * DMODEL + csw * 8,
                                  &Ksn[(16 * w + 8 * i) * 64]);
                GLOBAL_LOAD_LDS16(VT + vbase + (size_t)row * SEQ + kk0 + csw * 8,
                                  &Vtn[(16 * w + 8 * i) * 64]);
            }
        }

        if (k0 <= qmax) {
            const bool q2 = (k0 + 32 <= qmax);
            bf16x8 pa0, pa1, pa2, pa3;
            QUADRANT(0, pa0, pa1);
            __builtin_amdgcn_s_setprio(1);
            PVSTEP(0, pa0); PVSTEP(1, pa1);
            __builtin_amdgcn_s_setprio(0);
            if (q2) {
                QUADRANT(1, pa2, pa3);
                __builtin_amdgcn_s_setprio(1);
                PVSTEP(2, pa2); PVSTEP(3, pa3);
                __builtin_amdgcn_s_setprio(0);
            }
        }
        asm volatile("s_waitcnt vmcnt(0)" ::: "memory");
        __builtin_amdgcn_s_barrier();
    }
#undef QUADRANT
#undef PVSTEP

    // ---- finalize l (cross-half reduce, through LDS to reindex q)
    lsum += __shfl_xor(lsum, 32, 64);
    if (lane < 32) lS[32 * w + lane] = lsum;
    __syncthreads();

    // ---- writeout: O / l   (C layout: col=l31=d-local, row=(r&3)+8*(r>>2)+4*hl)
    #pragma unroll
    for (int g = 0; g < 4; g++) {
        f32x4 lv = *(const f32x4*)&lS[32 * w + 8 * g + 4 * hl];
        #pragma unroll
        for (int rr = 0; rr < 4; rr++) {
            int qg2 = q0 + 32 * w + rr + 8 * g + 4 * hl;
            float inv = 1.0f / lv[rr];
            #pragma unroll
            for (int dh = 0; dh < 2; dh++) {
                float o = oacc[dh][4 * g + rr] * inv;
                O[gbase + (size_t)qg2 * DMODEL + 32 * dh + l31] = f2bf(o);
            }
        }
    }
}

// ---------------------------------------------------------------------------
extern "C" void kernel_launch(void* const* d_in, const int* in_sizes, int n_in,
                              void* d_out, int out_size, void* d_ws, size_t ws_size,
                              hipStream_t stream)
{
    const float* x  = (const float*)d_in[0];
    const float* Wq = (const float*)d_in[1];
    const float* bq = (const float*)d_in[2];
    const float* Wk = (const float*)d_in[3];
    const float* bk = (const float*)d_in[4];
    const float* Wv = (const float*)d_in[5];
    const float* bv = (const float*)d_in[6];
    const float* Wo = (const float*)d_in[7];
    const float* bo = (const float*)d_in[8];

    u16* wsp = (u16*)d_ws;
    u16* xb  = wsp;                    // 8388608
    u16* Wqb = wsp + 8388608;          // 1048576 each (Wq,Wk,Wv contiguous)
    u16* Wkb = Wqb + 1048576;
    u16* Wvb = Wkb + 1048576;
    u16* Wob = Wvb + 1048576;
    u16* Qb  = Wob + 1048576;          // 8388608 each
    u16* Kb  = Qb + 8388608;
    u16* Vb  = Kb + 8388608;           // holds V^T[b][h][d][s]
    u16* Ab  = Vb + 8388608;

    convert_inputs<<<12288, 256, 0, stream>>>(x, Wq, Wk, Wv, Wo, xb);

    gemm_mfma<1><<<384, 512, 0, stream>>>(xb, Wqb, Wkb, Wvb, bq, bk, bv,
                                          Qb, Kb, Vb, nullptr);

    attn_mfma<<<1024, 256, 0, stream>>>(Qb, Kb, Vb, Ab);

    gemm_mfma<0><<<128, 512, 0, stream>>>(Ab, Wob, nullptr, nullptr, bo, nullptr, nullptr,
                                          nullptr, nullptr, nullptr, (float*)d_out);
}

// Round 5
// 254.283 us; speedup vs baseline: 1.0437x; 1.0437x over previous
//
#include <hip/hip_runtime.h>
#include <math.h>

// Problem constants (B,S,D,H) = (4,2048,1024,16), HD=64
#define BATCH 4
#define SEQ   2048
#define DMODEL 1024
#define NHEAD 16
#define HDIM  64
#define MROWS (BATCH*SEQ)   // 8192

typedef unsigned short u16;
typedef unsigned int   u32;

using bf16x8 = __attribute__((ext_vector_type(8))) short;
using f32x4  = __attribute__((ext_vector_type(4))) float;
using f32x16 = __attribute__((ext_vector_type(16))) float;
using u32x4  = __attribute__((ext_vector_type(4))) unsigned int;

__device__ __forceinline__ u16 f2bf(float f) {
    u32 u = __float_as_uint(f);
    u += 0x7fffu + ((u >> 16) & 1u);
    return (u16)(u >> 16);
}
__device__ __forceinline__ u32 pack2bf(float a, float b) {
    u32 ua = __float_as_uint(a); ua += 0x7fffu + ((ua >> 16) & 1u);
    u32 ub = __float_as_uint(b); ub += 0x7fffu + ((ub >> 16) & 1u);
    return (ua >> 16) | (ub & 0xffff0000u);
}
// packed f32->bf16x2 via HW instruction (src0 -> low half)
__device__ __forceinline__ u32 cvtpk(float a, float b) {
    u32 r;
    asm("v_cvt_pk_bf16_f32 %0, %1, %2" : "=v"(r) : "v"(a), "v"(b));
    return r;
}
// swap upper 32 lanes of a with lower 32 lanes of b
#define PLSWAP(a, b) asm("v_permlane32_swap_b32 %0, %1" : "+v"(a), "+v"(b))

// async global->LDS, 16 B per lane; LDS dest = wave-uniform base + lane*16
#define GLOBAL_LOAD_LDS16(gp, lp)                                              \
    __builtin_amdgcn_global_load_lds(                                          \
        (const __attribute__((address_space(1))) void*)(gp),                   \
        (__attribute__((address_space(3))) void*)(lp), 16, 0, 0)

// ---------------------------------------------------------------------------
// Convert x (8.4M) + Wq/Wk/Wv/Wo (1M each) fp32 -> bf16 into contiguous dst.
// ---------------------------------------------------------------------------
__global__ __launch_bounds__(256) void convert_inputs(
    const float* __restrict__ x,  const float* __restrict__ wq,
    const float* __restrict__ wk, const float* __restrict__ wv,
    const float* __restrict__ wo, u16* __restrict__ dst)
{
    long long i4 = ((long long)blockIdx.x * 256 + threadIdx.x) * 4;
    const float* src; long long off;
    if (i4 < 8388608LL) { src = x; off = i4; }
    else {
        long long j = i4 - 8388608LL;
        int seg = (int)(j >> 20);
        off = j & 1048575LL;
        src = (seg == 0) ? wq : (seg == 1) ? wk : (seg == 2) ? wv : wo;
    }
    float4 v = *(const float4*)(src + off);
    u32 lo = (u32)f2bf(v.x) | ((u32)f2bf(v.y) << 16);
    u32 hi = (u32)f2bf(v.z) | ((u32)f2bf(v.w) << 16);
    *(uint2*)(dst + i4) = make_uint2(lo, hi);
}

// ---------------------------------------------------------------------------
// QK GEMM — 256x256 8-phase schedule (R4-proven), N=2048 fused over Wq|Wk
// (contiguous rows 0..2047). Grid = 32m x 8n = 256 blocks = 1 full round.
// Epilogue: RoPE; Q-tiles (bn<1024) additionally scaled by 0.125*log2e.
// ---------------------------------------------------------------------------
__global__ __launch_bounds__(512) void gemm_qk(
    const u16* __restrict__ A, const u16* __restrict__ Wqk,
    const float* __restrict__ bq_, const float* __restrict__ bk_,
    u16* __restrict__ Cq_, u16* __restrict__ Ck_)
{
    // A: [2 dbuf][256][64] @ 0 ; B: [2 dbuf][256][64] @ 32768 (shorts)
    __shared__ __align__(16) u16 smem[65536];   // 128 KiB

    const int t    = threadIdx.x;
    const int lane = t & 63;
    const int w    = t >> 6;        // 0..7
    const int quad = lane >> 4;
    const int l15  = lane & 15;
    const int wm   = w >> 2;        // 0..1 (M)
    const int wn   = w & 3;         // 0..3 (N)

    const int bx  = blockIdx.x;
    const int xcd = bx & 7;
    const int i_  = bx >> 3;
    const int bml = i_ & 3;
    const int n_  = i_ >> 2;        // 0..7

    const int bm = (xcd * 4 + bml) * 256;
    const int bn = n_ * 256;

    const bool  isq  = (bn < 1024);
    const float* bias = isq ? bq_ : bk_;
    u16*         Cb   = isq ? Cq_ : Ck_;
    const int    bnl  = bn & 1023;

    const int sr8 = lane >> 3;
    const int scl = (lane & 7) ^ sr8;
    const u16* gA = A   + (size_t)(bm + 8 * w + sr8) * DMODEL + scl * 8;
    const u16* gB = Wqk + (size_t)(bn + 8 * w + sr8) * DMODEL + scl * 8;

#define STG_A(rg, kt, bs)                                                      \
    GLOBAL_LOAD_LDS16(gA + (size_t)(rg) * 64 * DMODEL + (kt) * 64,             \
                      &smem[(bs) * 16384 + ((rg) * 64 + 8 * w) * 64])
#define STG_B(rg, kt, bs)                                                      \
    GLOBAL_LOAD_LDS16(gB + (size_t)(rg) * 64 * DMODEL + (kt) * 64,             \
                      &smem[32768 + (bs) * 16384 + ((rg) * 64 + 8 * w) * 64])

    // ---- prologue: tile0 (buf0) all 8 halves; tile1 (buf1) first 6 halves
    STG_B(0, 0, 0); STG_B(1, 0, 0); STG_B(2, 0, 0); STG_B(3, 0, 0);
    STG_A(0, 0, 0); STG_A(2, 0, 0); STG_A(1, 0, 0); STG_A(3, 0, 0);
    STG_B(0, 1, 1); STG_B(1, 1, 1); STG_B(2, 1, 1); STG_B(3, 1, 1);
    STG_A(0, 1, 1); STG_A(2, 1, 1);
    asm volatile("s_waitcnt vmcnt(6)" ::: "memory");   // tile 0 landed
    __builtin_amdgcn_s_barrier();

    const int cA0 = (quad ^ (l15 & 7)) * 8;   // K-half0 chunk offset; half1 = ^32

    f32x4 acc[8][4] = {};
    bf16x8 bfr[4][2];

#define LOAD_B(Bb) {                                                           \
    _Pragma("unroll")                                                          \
    for (int j = 0; j < 4; ++j) {                                              \
        bfr[j][0] = *(const bf16x8*)&(Bb)[(wn * 64 + 16 * j + l15) * 64 + cA0];\
        bfr[j][1] = *(const bf16x8*)&(Bb)[(wn * 64 + 16 * j + l15) * 64 + (cA0 ^ 32)];\
    } }
#define PHASE(q, Ab, Bb, STAGES, CKPT) {                                       \
    bf16x8 af_[2][2];                                                          \
    if ((q) == 0) LOAD_B(Bb);                                                  \
    _Pragma("unroll")                                                          \
    for (int ii = 0; ii < 2; ++ii) {                                           \
        const int r_ = (wm * 128 + (q) * 32 + 16 * ii + l15) * 64;             \
        af_[ii][0] = *(const bf16x8*)&(Ab)[r_ + cA0];                          \
        af_[ii][1] = *(const bf16x8*)&(Ab)[r_ + (cA0 ^ 32)];                   \
    }                                                                          \
    STAGES;                                                                    \
    __builtin_amdgcn_s_barrier();                                              \
    asm volatile("s_waitcnt lgkmcnt(0)" ::: "memory");                         \
    __builtin_amdgcn_sched_barrier(0);                                         \
    __builtin_amdgcn_s_setprio(1);                                             \
    _Pragma("unroll")                                                          \
    for (int ii = 0; ii < 2; ++ii)                                             \
        _Pragma("unroll")                                                      \
        for (int j = 0; j < 4; ++j) {                                          \
            acc[2*(q)+ii][j] = __builtin_amdgcn_mfma_f32_16x16x32_bf16(        \
                af_[ii][0], bfr[j][0], acc[2*(q)+ii][j], 0, 0, 0);             \
            acc[2*(q)+ii][j] = __builtin_amdgcn_mfma_f32_16x16x32_bf16(        \
                af_[ii][1], bfr[j][1], acc[2*(q)+ii][j], 0, 0, 0);             \
        }                                                                      \
    __builtin_amdgcn_s_setprio(0);                                             \
    CKPT;                                                                      \
    __builtin_amdgcn_s_barrier();                                              \
}

    #pragma unroll 1
    for (int i = 0; i < 8; ++i) {
        const bool st = (i < 7);
        const int  kn = 2 * i + 2, kn3 = 2 * i + 3, ko = 2 * i + 1;
        // ---- K-tile 2i from buf0
        {
            const u16* Ab = smem;
            const u16* Bb = smem + 32768;
            PHASE(0, Ab, Bb, { STG_A(1, ko, 1); STG_A(3, ko, 1); }, {});
            PHASE(1, Ab, Bb, { if (st) { STG_B(0, kn, 0); STG_B(1, kn, 0); } }, {});
            PHASE(2, Ab, Bb, { if (st) { STG_B(2, kn, 0); STG_B(3, kn, 0); } }, {});
            PHASE(3, Ab, Bb, { if (st) { STG_A(0, kn, 0); STG_A(2, kn, 0); } },
                  { if (st) asm volatile("s_waitcnt vmcnt(6)" ::: "memory");
                    else    asm volatile("s_waitcnt vmcnt(0)" ::: "memory"); });
        }
        // ---- K-tile 2i+1 from buf1
        {
            const u16* Ab = smem + 16384;
            const u16* Bb = smem + 32768 + 16384;
            PHASE(0, Ab, Bb, { if (st) { STG_A(1, kn, 0); STG_A(3, kn, 0); } }, {});
            PHASE(1, Ab, Bb, { if (st) { STG_B(0, kn3, 1); STG_B(1, kn3, 1); } }, {});
            PHASE(2, Ab, Bb, { if (st) { STG_B(2, kn3, 1); STG_B(3, kn3, 1); } }, {});
            PHASE(3, Ab, Bb, { if (st) { STG_A(0, kn3, 1); STG_A(2, kn3, 1); } },
                  { if (st) asm volatile("s_waitcnt vmcnt(6)" ::: "memory");
                    else    asm volatile("s_waitcnt vmcnt(0)" ::: "memory"); });
        }
    }
#undef PHASE
#undef LOAD_B
#undef STG_A
#undef STG_B

    // ---- RoPE epilogue: wave's 64-col span = one head; pair (d,d+32) = j,(j+2)
    const int wrow = wm * 128;
    const int wcol = wn * 64;
    float bvv[4];
    #pragma unroll
    for (int j = 0; j < 4; j++) bvv[j] = bias[bnl + wcol + 16 * j + l15];

    const float qscale = isq ? 0.18033688011112042f : 1.0f;   // 0.125*log2e or 1
    float inv[2];
    #pragma unroll
    for (int j = 0; j < 2; j++) {
        int d = 16 * j + l15;                              // 0..31
        inv[j] = exp2f(-(float)d * 0.4152410118609203f);   // 10000^(-d/32)
    }
    #pragma unroll
    for (int ri = 0; ri < 8; ri++)
        #pragma unroll
        for (int r = 0; r < 4; r++) {
            int mg = bm + wrow + 16 * ri + quad * 4 + r;
            int s  = mg & (SEQ - 1);
            #pragma unroll
            for (int j = 0; j < 2; j++) {
                float f = (float)s * inv[j];
                float sn, cs;
                __sincosf(f, &sn, &cs);
                float a1 = acc[ri][j][r]     + bvv[j];
                float a2 = acc[ri][j + 2][r] + bvv[j + 2];
                float o1 = (a1 * cs - a2 * sn) * qscale;
                float o2 = (a2 * cs + a1 * sn) * qscale;
                Cb[(size_t)mg * DMODEL + bnl + wcol + 16 * j       + l15] = f2bf(o1);
                Cb[(size_t)mg * DMODEL + bnl + wcol + 16 * (j + 2) + l15] = f2bf(o2);
            }
        }
}

// ---------------------------------------------------------------------------
// NJ=2 GEMM — BM=256 x BN=128, BK=64, 512 thr = 8 waves (2M x 4N), per-wave
// 128x32, acc[8][2]. 3-deep LDS rotation (A 3x16384 + B 3x8192 shorts =
// 144 KiB), 2 fine phases/tile {12|8 ds_read; 3 global_load_lds; barrier;
// lgkmcnt(0)+sched_barrier; setprio 16 MFMA; [vmcnt(6) at q1]; barrier}.
// Grid = 32m x 8n = 256 blocks = 1 full round.
// EPI 0: fp32 + bias (final projection). EPI 1: V^T[b][h][d][s] store.
// ---------------------------------------------------------------------------
template<int EPI>
__global__ __launch_bounds__(512) void gemm_nj2(
    const u16* __restrict__ A, const u16* __restrict__ W,
    const float* __restrict__ bias_, u16* __restrict__ Cb, float* __restrict__ Cf)
{
    // A: 3 x [256][64] @ 0 ; B: 3 x [128][64] @ 49152 (shorts)
    __shared__ __align__(16) u16 smem[73728];   // 144 KiB

    const int t    = threadIdx.x;
    const int lane = t & 63;
    const int w    = t >> 6;
    const int quad = lane >> 4;
    const int l15  = lane & 15;
    const int wm   = w >> 2;        // 0..1
    const int wn   = w & 3;         // 0..3

    const int bx  = blockIdx.x;
    const int xcd = bx & 7;
    const int i_  = bx >> 3;
    const int bml = i_ & 3;
    const int n_  = i_ >> 2;        // 0..7

    const int bm = (xcd * 4 + bml) * 256;
    const int bn = n_ * 128;

    const int sr8 = lane >> 3;
    const int scl = (lane & 7) ^ sr8;
    const u16* gA = A + (size_t)(bm + 8 * w + sr8) * DMODEL + scl * 8;
    const u16* gB = W + (size_t)(bn + 8 * w + sr8) * DMODEL + scl * 8;

#define STG_A(rg, kt, bs)                                                      \
    GLOBAL_LOAD_LDS16(gA + (size_t)(rg) * 64 * DMODEL + (kt) * 64,             \
                      &smem[(bs) * 16384 + ((rg) * 64 + 8 * w) * 64])
#define STG_B(rg, kt, bs)                                                      \
    GLOBAL_LOAD_LDS16(gB + (size_t)(rg) * 64 * DMODEL + (kt) * 64,             \
                      &smem[49152 + (bs) * 8192 + ((rg) * 64 + 8 * w) * 64])

    // ---- prologue: tiles 0 (buf0) and 1 (buf1), 6 loads each
    STG_B(0, 0, 0); STG_B(1, 0, 0);
    STG_A(0, 0, 0); STG_A(1, 0, 0); STG_A(2, 0, 0); STG_A(3, 0, 0);
    STG_B(0, 1, 1); STG_B(1, 1, 1);
    STG_A(0, 1, 1); STG_A(1, 1, 1); STG_A(2, 1, 1); STG_A(3, 1, 1);
    asm volatile("s_waitcnt vmcnt(6)" ::: "memory");   // tile 0 landed
    __builtin_amdgcn_s_barrier();

    const int cA0 = (quad ^ (l15 & 7)) * 8;

    f32x4 acc[8][2] = {};

    int c = 0;
    #pragma unroll 1
    for (int kt = 0; kt < 16; ++kt) {
        const u16* Ab = smem + c * 16384;
        const u16* Bb = smem + 49152 + c * 8192;
        const int  sb = (c >= 1) ? c - 1 : 2;   // (c+2)%3
        const int  ks = kt + 2;
        const bool st = (kt < 14);

        bf16x8 bfr[2][2], af[4][2];

        // ---- q0: rows 0..63 of wave tile, both K-halves; load B frags
        #pragma unroll
        for (int j = 0; j < 2; ++j) {
            bfr[j][0] = *(const bf16x8*)&Bb[(wn * 32 + 16 * j + l15) * 64 + cA0];
            bfr[j][1] = *(const bf16x8*)&Bb[(wn * 32 + 16 * j + l15) * 64 + (cA0 ^ 32)];
        }
        #pragma unroll
        for (int ii = 0; ii < 4; ++ii) {
            const int r_ = (wm * 128 + 16 * ii + l15) * 64;
            af[ii][0] = *(const bf16x8*)&Ab[r_ + cA0];
            af[ii][1] = *(const bf16x8*)&Ab[r_ + (cA0 ^ 32)];
        }
        if (st) { STG_B(0, ks, sb); STG_B(1, ks, sb); STG_A(0, ks, sb); }
        __builtin_amdgcn_s_barrier();
        asm volatile("s_waitcnt lgkmcnt(0)" ::: "memory");
        __builtin_amdgcn_sched_barrier(0);
        __builtin_amdgcn_s_setprio(1);
        #pragma unroll
        for (int ii = 0; ii < 4; ++ii)
            #pragma unroll
            for (int j = 0; j < 2; ++j) {
                acc[ii][j] = __builtin_amdgcn_mfma_f32_16x16x32_bf16(
                    af[ii][0], bfr[j][0], acc[ii][j], 0, 0, 0);
                acc[ii][j] = __builtin_amdgcn_mfma_f32_16x16x32_bf16(
                    af[ii][1], bfr[j][1], acc[ii][j], 0, 0, 0);
            }
        __builtin_amdgcn_s_setprio(0);
        __builtin_amdgcn_s_barrier();

        // ---- q1: rows 64..127 of wave tile
        #pragma unroll
        for (int ii = 0; ii < 4; ++ii) {
            const int r_ = (wm * 128 + 64 + 16 * ii + l15) * 64;
            af[ii][0] = *(const bf16x8*)&Ab[r_ + cA0];
            af[ii][1] = *(const bf16x8*)&Ab[r_ + (cA0 ^ 32)];
        }
        if (st) { STG_A(1, ks, sb); STG_A(2, ks, sb); STG_A(3, ks, sb); }
        __builtin_amdgcn_s_barrier();
        asm volatile("s_waitcnt lgkmcnt(0)" ::: "memory");
        __builtin_amdgcn_sched_barrier(0);
        __builtin_amdgcn_s_setprio(1);
        #pragma unroll
        for (int ii = 0; ii < 4; ++ii)
            #pragma unroll
            for (int j = 0; j < 2; ++j) {
                acc[4 + ii][j] = __builtin_amdgcn_mfma_f32_16x16x32_bf16(
                    af[ii][0], bfr[j][0], acc[4 + ii][j], 0, 0, 0);
                acc[4 + ii][j] = __builtin_amdgcn_mfma_f32_16x16x32_bf16(
                    af[ii][1], bfr[j][1], acc[4 + ii][j], 0, 0, 0);
            }
        __builtin_amdgcn_s_setprio(0);
        if (st) asm volatile("s_waitcnt vmcnt(6)" ::: "memory");
        else    asm volatile("s_waitcnt vmcnt(0)" ::: "memory");
        __builtin_amdgcn_s_barrier();

        c = (c == 2) ? 0 : c + 1;
    }
#undef STG_A
#undef STG_B

    // ---- epilogue: rows bm + wm*128 + 16ri + quad*4 + r; cols bn + wn*32 + 16j + l15
    const int wrow = wm * 128;
    const int wcol = wn * 32;
    float bvv[2];
    #pragma unroll
    for (int j = 0; j < 2; j++) bvv[j] = bias_[bn + wcol + 16 * j + l15];

    if constexpr (EPI == 0) {
        #pragma unroll
        for (int ri = 0; ri < 8; ri++)
            #pragma unroll
            for (int r = 0; r < 4; r++) {
                int mg = bm + wrow + 16 * ri + quad * 4 + r;
                #pragma unroll
                for (int j = 0; j < 2; j++)
                    Cf[(size_t)mg * DMODEL + bn + wcol + 16 * j + l15] = acc[ri][j][r] + bvv[j];
            }
    } else {
        // ---- V^T store: transpose 256(s) x 128(d) tile via LDS.
        // T logical [row=d 0..127][col=s 0..255] bf16 (512-B rows),
        // byte-swizzled: byte ^= (row&7)<<4 (16-B granular).
        u16* T = smem;   // buffers dead; 64 KiB of 144
        __syncthreads();
        #pragma unroll
        for (int ri = 0; ri < 8; ri++) {
            #pragma unroll
            for (int j = 0; j < 2; j++) {
                int col = wrow + 16 * ri + quad * 4;  // s-local (r adds 0..3)
                int row = wcol + 16 * j + l15;        // d-local 0..127
                u32 lo = pack2bf(acc[ri][j][0] + bvv[j], acc[ri][j][1] + bvv[j]);
                u32 hi = pack2bf(acc[ri][j][2] + bvv[j], acc[ri][j][3] + bvv[j]);
                *(uint2*)((char*)T + row * 512 + ((col * 2) ^ ((row & 7) << 4)))
                    = make_uint2(lo, hi);
            }
        }
        __syncthreads();
        {
            int row = t >> 2, colc = t & 3;           // 128 rows x 4 chunks
            int hgl = (bn + row) >> 6;
            int dl  = (bn + row) & 63;
            int bb  = bm >> 11;
            size_t obase = (((size_t)(bb * NHEAD + hgl)) * HDIM + dl) * SEQ
                         + (bm & (SEQ - 1)) + colc * 64;
            #pragma unroll
            for (int k = 0; k < 8; k++) {
                uint4 vv = *(const uint4*)((const char*)T + row * 512
                             + ((colc * 128 + k * 16) ^ ((row & 7) << 4)));
                *(uint4*)(Cb + obase + k * 8) = vv;
            }
        }
    }
}

// ---------------------------------------------------------------------------
// MFMA flash attention v3: 32x32x16, 128 q-rows/block, max-free softmax.
// S^T = K*Q^T so P is lane-local; P->bf16 A-frags built IN REGISTER via
// v_cvt_pk_bf16_f32 + v_permlane32_swap_b32 (no P LDS bounce).  V arrives
// pre-transposed (V^T[b][h][d][s]) and is staged like K via global_load_lds.
// K/V double-buffered, single barrier + vmcnt(0) per tile; buffer 1 aliases
// the dead Q staging area -> 33,280 B LDS, 4 blocks/CU (all 1024 resident).
// ---------------------------------------------------------------------------
__global__ __launch_bounds__(256) void attn_mfma(
    const u16* __restrict__ Q, const u16* __restrict__ K,
    const u16* __restrict__ VT, u16* __restrict__ O)
{
    __shared__ __align__(16) u16 smem[16640];   // 33,280 B
    u16* const Qs  = smem;                      // bytes [0,16384)
    u16* const Ks0 = smem + 8192;               // [16384,24576)
    u16* const Ks1 = smem;                      // alias Qs lo half [0,8192)
    u16* const Vt0 = smem + 12288;              // [24576,32768)
    u16* const Vt1 = smem + 4096;               // alias Qs hi half [8192,16384)
    float* const lS = (float*)(smem + 16384);   // [32768,33280)

    const int t    = threadIdx.x;
    const int lane = t & 63;
    const int w    = t >> 6;
    const int l31  = lane & 31;
    const int hl   = lane >> 5;         // 0/1
    const int bid  = blockIdx.x;
    const int bh   = bid & 63;
    // per-CU balanced qt map: CU hosts x, x+4, x+8, x+12 -> equal tile sums
    const int x_   = bid >> 6, g_ = x_ >> 2, r_ = x_ & 3;
    const int qt   = (g_ == 0) ? 15 - r_ : (g_ == 1) ? 8 + r_
                   : (g_ == 2) ? 4 + r_ : 3 - r_;
    const int h    = bh & (NHEAD - 1);
    const int b    = bh >> 4;
    const int q0   = qt * 128;

    const size_t gbase = ((size_t)b * SEQ) * DMODEL + h * HDIM;
    const size_t vbase = ((size_t)(b * NHEAD + h)) * HDIM * SEQ;

    const int rl  = lane >> 3;
    const int csw = (lane & 7) ^ rl;    // pre-swizzled source chunk

    // ---- prologue: stage Q (4 issues) + K/V^T tile 0 (2+2 issues)
    #pragma unroll
    for (int i = 0; i < 4; i++) {
        int row = 32 * w + 8 * i + rl;
        GLOBAL_LOAD_LDS16(Q + gbase + (size_t)(q0 + row) * DMODEL + csw * 8,
                          &Qs[(32 * w + 8 * i) * 64]);
    }
    #pragma unroll
    for (int i = 0; i < 2; i++) {
        int row = 16 * w + 8 * i + rl;
        GLOBAL_LOAD_LDS16(K + gbase + (size_t)row * DMODEL + csw * 8,
                          &Ks0[(16 * w + 8 * i) * 64]);
        GLOBAL_LOAD_LDS16(VT + vbase + (size_t)row * SEQ + csw * 8,
                          &Vt0[(16 * w + 8 * i) * 64]);
    }
    __syncthreads();

    // ---- hoist Q B-fragments: B[k][n=q], k = hl*8+e (+16*stp)
    bf16x8 qf[4];
    {
        int row = 32 * w + l31;
        #pragma unroll
        for (int s = 0; s < 4; s++) {
            int c = (hl + 2 * s) ^ (row & 7);
            qf[s] = *(const bf16x8*)&Qs[row * 64 + c * 8];
        }
    }
    __syncthreads();   // Qs dead; aliased buffer 1 may now be staged

    float lsum = 0.0f;
    f32x16 oacc[2] = {};
    const int qg   = q0 + 32 * w + l31;
    const int qmax = q0 + 32 * w + 31;

// S^T quadrant KRH: 4 MFMA, mask, exp2, tree-sum, in-register P->bf16 frags.
#define QUADRANT(KRH, F0, F1) do {                                             \
    f32x16 s_ = {};                                                            \
    __builtin_amdgcn_s_setprio(1);                                             \
    _Pragma("unroll")                                                          \
    for (int stp_ = 0; stp_ < 4; ++stp_) {                                     \
        int c_ = ((hl + 2 * stp_) ^ (l31 & 7)) * 8;                            \
        bf16x8 ka_ = *(const bf16x8*)&Ksb[(32 * (KRH) + l31) * 64 + c_];       \
        s_ = __builtin_amdgcn_mfma_f32_32x32x16_bf16(ka_, qf[stp_], s_, 0, 0, 0);\
    }                                                                          \
    __builtin_amdgcn_s_setprio(0);                                             \
    if (k0 + 32 * (KRH) + 31 > q0 + 32 * w) {                                  \
        _Pragma("unroll")                                                      \
        for (int rr_ = 0; rr_ < 16; ++rr_) {                                   \
            int krg_ = k0 + 32 * (KRH) + (rr_ & 3) + 8 * (rr_ >> 2) + 4 * hl;  \
            if (krg_ > qg) s_[rr_] = -1e30f;                                   \
        }                                                                      \
    }                                                                          \
    float pv_[16];                                                             \
    _Pragma("unroll")                                                          \
    for (int rr_ = 0; rr_ < 16; ++rr_) pv_[rr_] = __builtin_amdgcn_exp2f(s_[rr_]);\
    lsum += ((pv_[0]+pv_[1])+(pv_[2]+pv_[3])) + ((pv_[4]+pv_[5])+(pv_[6]+pv_[7]))\
          + ((pv_[8]+pv_[9])+(pv_[10]+pv_[11])) + ((pv_[12]+pv_[13])+(pv_[14]+pv_[15]));\
    u32 k01_ = cvtpk(pv_[0], pv_[1]),   k23_ = cvtpk(pv_[2], pv_[3]);          \
    u32 k45_ = cvtpk(pv_[4], pv_[5]),   k67_ = cvtpk(pv_[6], pv_[7]);          \
    u32 k89_ = cvtpk(pv_[8], pv_[9]),   kab_ = cvtpk(pv_[10], pv_[11]);        \
    u32 kcd_ = cvtpk(pv_[12], pv_[13]), kef_ = cvtpk(pv_[14], pv_[15]);        \
    PLSWAP(k01_, k45_); PLSWAP(k23_, k67_);                                    \
    PLSWAP(k89_, kcd_); PLSWAP(kab_, kef_);                                    \
    { union { u32x4 u; bf16x8 v; } c0_; c0_.u = (u32x4){k01_, k23_, k45_, k67_};\
      F0 = c0_.v; }                                                            \
    { union { u32x4 u; bf16x8 v; } c1_; c1_.u = (u32x4){k89_, kab_, kcd_, kef_};\
      F1 = c1_.v; }                                                            \
} while (0)

#define PVSTEP(STP, PF) do {                                                   \
    int c_ = ((hl + 2 * (STP)) ^ (l31 & 7)) * 8;                               \
    bf16x8 v0_ = *(const bf16x8*)&Vtb[l31 * 64 + c_];                          \
    bf16x8 v1_ = *(const bf16x8*)&Vtb[(32 + l31) * 64 + c_];                   \
    oacc[0] = __builtin_amdgcn_mfma_f32_32x32x16_bf16(PF, v0_, oacc[0], 0, 0, 0);\
    oacc[1] = __builtin_amdgcn_mfma_f32_32x32x16_bf16(PF, v1_, oacc[1], 0, 0, 0);\
} while (0)

    const int ktn = 2 * qt + 2;
    for (int kt = 0; kt < ktn; kt++) {
        const int k0 = kt * 64;
        u16* const Ksb = (kt & 1) ? Ks1 : Ks0;
        u16* const Vtb = (kt & 1) ? Vt1 : Vt0;

        // prefetch next tile into the other buffer (issue-early)
        if (kt + 1 < ktn) {
            u16* const Ksn = (kt & 1) ? Ks0 : Ks1;
            u16* const Vtn = (kt & 1) ? Vt0 : Vt1;
            const size_t kk0 = (size_t)(kt + 1) * 64;
            #pragma unroll
            for (int i = 0; i < 2; i++) {
                int row = 16 * w + 8 * i + rl;
                GLOBAL_LOAD_LDS16(K + gbase + (kk0 + row) * DMODEL + csw * 8,
                                  &Ksn[(16 * w + 8 * i) * 64]);
                GLOBAL_LOAD_LDS16(VT + vbase + (size_t)row * SEQ + kk0 + csw * 8,
                                  &Vtn[(16 * w + 8 * i) * 64]);
            }
        }

        if (k0 <= qmax) {
            const bool q2 = (k0 + 32 <= qmax);
            bf16x8 pa0, pa1, pa2, pa3;
            QUADRANT(0, pa0, pa1);
            __builtin_amdgcn_s_setprio(1);
            PVSTEP(0, pa0); PVSTEP(1, pa1);
            __builtin_amdgcn_s_setprio(0);
            if (q2) {
                QUADRANT(1, pa2, pa3);
                __builtin_amdgcn_s_setprio(1);
                PVSTEP(2, pa2); PVSTEP(3, pa3);
                __builtin_amdgcn_s_setprio(0);
            }
        }
        asm volatile("s_waitcnt vmcnt(0)" ::: "memory");
        __builtin_amdgcn_s_barrier();
    }
#undef QUADRANT
#undef PVSTEP

    // ---- finalize l (cross-half reduce, through LDS to reindex q)
    lsum += __shfl_xor(lsum, 32, 64);
    if (lane < 32) lS[32 * w + lane] = lsum;
    __syncthreads();

    // ---- writeout: O / l   (C layout: col=l31=d-local, row=(r&3)+8*(r>>2)+4*hl)
    #pragma unroll
    for (int g = 0; g < 4; g++) {
        f32x4 lv = *(const f32x4*)&lS[32 * w + 8 * g + 4 * hl];
        #pragma unroll
        for (int rr = 0; rr < 4; rr++) {
            int qg2 = q0 + 32 * w + rr + 8 * g + 4 * hl;
            float inv = 1.0f / lv[rr];
            #pragma unroll
            for (int dh = 0; dh < 2; dh++) {
                float o = oacc[dh][4 * g + rr] * inv;
                O[gbase + (size_t)qg2 * DMODEL + 32 * dh + l31] = f2bf(o);
            }
        }
    }
}

// ---------------------------------------------------------------------------
extern "C" void kernel_launch(void* const* d_in, const int* in_sizes, int n_in,
                              void* d_out, int out_size, void* d_ws, size_t ws_size,
                              hipStream_t stream)
{
    const float* x  = (const float*)d_in[0];
    const float* Wq = (const float*)d_in[1];
    const float* bq = (const float*)d_in[2];
    const float* Wk = (const float*)d_in[3];
    const float* bk = (const float*)d_in[4];
    const float* Wv = (const float*)d_in[5];
    const float* bv = (const float*)d_in[6];
    const float* Wo = (const float*)d_in[7];
    const float* bo = (const float*)d_in[8];

    u16* wsp = (u16*)d_ws;
    u16* xb  = wsp;                    // 8388608
    u16* Wqb = wsp + 8388608;          // 1048576 each (Wq,Wk,Wv contiguous)
    u16* Wkb = Wqb + 1048576;
    u16* Wvb = Wkb + 1048576;
    u16* Wob = Wvb + 1048576;
    u16* Qb  = Wob + 1048576;          // 8388608 each
    u16* Kb  = Qb + 8388608;
    u16* Vb  = Kb + 8388608;           // holds V^T[b][h][d][s]
    u16* Ab  = Vb + 8388608;

    convert_inputs<<<12288, 256, 0, stream>>>(x, Wq, Wk, Wv, Wo, xb);

    gemm_qk<<<256, 512, 0, stream>>>(xb, Wqb, bq, bk, Qb, Kb);

    gemm_nj2<1><<<256, 512, 0, stream>>>(xb, Wvb, bv, Vb, nullptr);

    attn_mfma<<<1024, 256, 0, stream>>>(Qb, Kb, Vb, Ab);

    gemm_nj2<0><<<256, 512, 0, stream>>>(Ab, Wob, bo, nullptr, (float*)d_out);
}